// Round 11
// baseline (783.094 us; speedup 1.0000x reference)
//
#include <hip/hip_runtime.h>
#include <math.h>

#define N_NODES 50000
#define N_EDGES 500000
#define NT 3
#define NRR 5
#define NH 8
#define DKH 16
#define DIM 128
#define NSEG (N_NODES * NRR)

// ---------------------------------------------------------------------------
// init: zero deg + cursor + cnts (contiguous int region, ~2 MB)
// ---------------------------------------------------------------------------
__global__ void init_ints(int* __restrict__ base, long n_ints) {
  long i = (long)blockIdx.x * blockDim.x + threadIdx.x;
  long stride = (long)gridDim.x * blockDim.x;
  for (long j = i; j < n_ints; j += stride) base[j] = 0;
}

// ---------------------------------------------------------------------------
// bucket nodes by type, LDS-preaggregated (3 global atomics per block, G12)
// ---------------------------------------------------------------------------
__global__ void bucket_nodes(const int* __restrict__ ntype, int* __restrict__ order,
                             int* __restrict__ bcnt) {
  __shared__ int lcnt[NT];
  __shared__ int lbase[NT];
  int tid = threadIdx.x;
  if (tid < NT) lcnt[tid] = 0;
  __syncthreads();
  int i = blockIdx.x * blockDim.x + tid;
  int t = -1, lp = 0;
  if (i < N_NODES) {
    t = ntype[i];
    lp = atomicAdd(&lcnt[t], 1);
  }
  __syncthreads();
  if (tid < NT) lbase[tid] = atomicAdd(&bcnt[tid], lcnt[tid]);
  __syncthreads();
  if (i < N_NODES) order[t * N_NODES + lbase[t] + lp] = i;
}

// ---------------------------------------------------------------------------
// segment CSR build: histogram over seg=(dst*R+etype), then UNORDERED range
// assignment (wave shfl_up scan + one global atomic per block).
// ---------------------------------------------------------------------------
__global__ void hist_seg(const int* __restrict__ dst, const int* __restrict__ etype,
                         int* __restrict__ deg) {
  int i = blockIdx.x * blockDim.x + threadIdx.x;
  if (i >= N_EDGES) return;
  atomicAdd(&deg[dst[i] * NRR + etype[i]], 1);   // 250K addrs, avg contention 2
}

__global__ void assign_seg(const int* __restrict__ deg, int* __restrict__ segstart,
                           int* __restrict__ gcursor) {
  int i = blockIdx.x * 256 + threadIdx.x;
  int lane = threadIdx.x & 63, wv = threadIdx.x >> 6;
  int d = (i < NSEG) ? deg[i] : 0;
  int s = d;                                  // inclusive scan within wave
  #pragma unroll
  for (int m = 1; m < 64; m <<= 1) {
    int v = __shfl_up(s, m, 64);
    if (lane >= m) s += v;
  }
  __shared__ int wsum[4];
  __shared__ int wbase[4];
  __shared__ int blockbase;
  if (lane == 63) wsum[wv] = s;
  __syncthreads();
  if (threadIdx.x == 0) {
    int acc = 0;
    #pragma unroll
    for (int w = 0; w < 4; w++) { wbase[w] = acc; acc += wsum[w]; }
    blockbase = atomicAdd(gcursor, acc);
  }
  __syncthreads();
  if (i < NSEG) segstart[i] = blockbase + wbase[wv] + (s - d);   // exclusive
}

__global__ void scatter_seg(const int* __restrict__ src, const int* __restrict__ dst,
                            const int* __restrict__ etype,
                            const int* __restrict__ segstart, int* __restrict__ cursor,
                            int* __restrict__ meta) {
  int i = blockIdx.x * blockDim.x + threadIdx.x;
  if (i >= N_EDGES) return;
  int seg = dst[i] * NRR + etype[i];
  int pos = segstart[seg] + atomicAdd(&cursor[seg], 1);
  meta[pos] = src[i];
}

// ---------------------------------------------------------------------------
// kqv_gemm: fused K/Q/V typed projections (R10 version, conflicts fixed).
// Lane tx owns cols [tx*4,+4) and [64+tx*4,+4); W staged 8 k-rows (4KB).
// k,v written interleaved per node (kv[n][0..127]=k, [128..255]=v).
// ---------------------------------------------------------------------------
__launch_bounds__(256)
__global__ void kqv_gemm(const float* __restrict__ x,
                         const float* __restrict__ Wk, const float* __restrict__ bk,
                         const float* __restrict__ Wq, const float* __restrict__ bq,
                         const float* __restrict__ Wv, const float* __restrict__ bv,
                         float* __restrict__ kv, float* __restrict__ qb,
                         const int* __restrict__ order, const int* __restrict__ bcnt) {
  int t = blockIdx.y;
  int cnt = bcnt[t];
  int base = blockIdx.x * 64;
  if (base >= cnt) return;

  __shared__ float xs[64][129];
  __shared__ __align__(16) float wsl[8 * 128];
  __shared__ int nids[64];

  int tid = threadIdx.x;
  if (tid < 64) {
    int idx = base + tid;
    nids[tid] = (idx < cnt) ? order[t * N_NODES + idx] : -1;
  }
  __syncthreads();

  #pragma unroll
  for (int i = 0; i < 8; i++) {
    int idx = tid + i * 256;
    int node = idx >> 5, c4 = idx & 31;
    int nid = nids[node];
    float4 v = make_float4(0.f, 0.f, 0.f, 0.f);
    if (nid >= 0) v = *(const float4*)(x + (size_t)nid * DIM + c4 * 4);
    xs[node][c4 * 4 + 0] = v.x;
    xs[node][c4 * 4 + 1] = v.y;
    xs[node][c4 * 4 + 2] = v.z;
    xs[node][c4 * 4 + 3] = v.w;
  }

  int tx = tid & 15;
  int ty = tid >> 4;
  const float* Ws[3] = {Wk, Wv, Wq};
  const float* bs[3] = {bk, bv, bq};

  for (int m = 0; m < 3; m++) {
    const float* wbase = Ws[m] + (size_t)t * DIM * DIM;
    float4 acc[4][2];
    #pragma unroll
    for (int j = 0; j < 4; j++) {
      acc[j][0] = make_float4(0.f, 0.f, 0.f, 0.f);
      acc[j][1] = make_float4(0.f, 0.f, 0.f, 0.f);
    }

    for (int ks = 0; ks < 16; ks++) {          // 8 k-rows per stage
      __syncthreads();
      *(float4*)&wsl[tid * 4] = *(const float4*)(wbase + ks * 1024 + tid * 4);
      __syncthreads();
      #pragma unroll
      for (int kk = 0; kk < 8; kk++) {
        float4 w0 = *(const float4*)&wsl[kk * 128 + tx * 4];
        float4 w1 = *(const float4*)&wsl[kk * 128 + 64 + tx * 4];
        #pragma unroll
        for (int j = 0; j < 4; j++) {
          float xv = xs[ty * 4 + j][ks * 8 + kk];
          acc[j][0].x += xv * w0.x; acc[j][0].y += xv * w0.y;
          acc[j][0].z += xv * w0.z; acc[j][0].w += xv * w0.w;
          acc[j][1].x += xv * w1.x; acc[j][1].y += xv * w1.y;
          acc[j][1].z += xv * w1.z; acc[j][1].w += xv * w1.w;
        }
      }
    }

    float4 b0 = *(const float4*)(bs[m] + t * DIM + tx * 4);
    float4 b1 = *(const float4*)(bs[m] + t * DIM + 64 + tx * 4);
    #pragma unroll
    for (int j = 0; j < 4; j++) {
      int nid = nids[ty * 4 + j];
      if (nid < 0) continue;
      float* ob = (m == 2) ? (qb + (size_t)nid * DIM)
                           : (kv + (size_t)nid * 256 + (m == 1 ? 128 : 0));
      *(float4*)(ob + tx * 4)      = make_float4(acc[j][0].x + b0.x, acc[j][0].y + b0.y,
                                                 acc[j][0].z + b0.z, acc[j][0].w + b0.w);
      *(float4*)(ob + 64 + tx * 4) = make_float4(acc[j][1].x + b1.x, acc[j][1].y + b1.y,
                                                 acc[j][1].z + b1.z, acc[j][1].w + b1.w);
    }
  }
}

// ---------------------------------------------------------------------------
// rel_gather v5: node-major, NO LDS, NO barriers, no hseg round-trip.
// Group (8 lanes = heads) owns one node; loops r=0..4 accumulating
//   tacc += (pv_r @ M_r) / den_r   for nonempty r, then writes
//   t[n,:] = tacc / max(cnt,1) ONCE (25.6 MB instead of 118 MB hseg+denom).
// A[r],M[r] read directly from global: at each r, lane c of EVERY group
// reads the same A[r][c] addresses -> broadcast-coalesced, L1/L2-resident
// (80 KB total). q read once per node. Edge math identical to v4.
// grid = ceil(N/32); block 256.
// ---------------------------------------------------------------------------
__launch_bounds__(256)
__global__ void rel_gather(const float* __restrict__ kv, const float* __restrict__ qmat,
                           const float* __restrict__ rel_att, const float* __restrict__ rel_msg,
                           const float* __restrict__ rel_pri,
                           const int* __restrict__ segstart, const int* __restrict__ deg,
                           const int* __restrict__ meta, float* __restrict__ tout) {
  int tid = threadIdx.x;
  int g = tid >> 3;                  // node slot 0..31
  int c = tid & 7;                   // head owned by this lane
  int n = blockIdx.x * 32 + g;
  if (n >= N_NODES) return;          // no LDS/barriers -> divergent exit ok

  const float4* qr = (const float4*)(qmat + (size_t)n * DIM + c * DKH);
  float4 q0 = qr[0], q1 = qr[1], q2 = qr[2], q3 = qr[3];

  float tacc[16];
  #pragma unroll
  for (int j = 0; j < 16; j++) tacc[j] = 0.f;
  float cnt = 0.f;

  for (int r = 0; r < NRR; r++) {
    int seg = n * NRR + r;
    int dg = deg[seg];
    if (dg == 0) continue;
    cnt += 1.f;
    int p0 = segstart[seg];
    float pri = rel_pri[r * NH + c] * 0.25f;   // fold 1/sqrt(16)

    // qa[d] = sum_f A[r,c][d][f] * q[f]  (global reads, L1/L2-broadcast)
    const float* Ab = rel_att + (size_t)(r * NH + c) * 256;
    float qa[16];
    #pragma unroll
    for (int d = 0; d < 16; d++) {
      const float4* ar = (const float4*)(Ab + d * 16);
      float4 a0 = ar[0], a1 = ar[1], a2 = ar[2], a3 = ar[3];
      qa[d] = a0.x*q0.x + a0.y*q0.y + a0.z*q0.z + a0.w*q0.w
            + a1.x*q1.x + a1.y*q1.y + a1.z*q1.z + a1.w*q1.w
            + a2.x*q2.x + a2.y*q2.y + a2.z*q2.z + a2.w*q2.w
            + a3.x*q3.x + a3.y*q3.y + a3.z*q3.z + a3.w*q3.w;
    }

    float den = 0.f;
    float pv[16];
    #pragma unroll
    for (int d = 0; d < 16; d++) pv[d] = 0.f;

#define SCORE(k0_, k1_, k2_, k3_) \
  (k0_.x*qa[0]  + k0_.y*qa[1]  + k0_.z*qa[2]  + k0_.w*qa[3]  \
 + k1_.x*qa[4]  + k1_.y*qa[5]  + k1_.z*qa[6]  + k1_.w*qa[7]  \
 + k2_.x*qa[8]  + k2_.y*qa[9]  + k2_.z*qa[10] + k2_.w*qa[11] \
 + k3_.x*qa[12] + k3_.y*qa[13] + k3_.z*qa[14] + k3_.w*qa[15])

#define PVADD(p_, v0_, v1_, v2_, v3_) \
  pv[0]  += p_*v0_.x; pv[1]  += p_*v0_.y; pv[2]  += p_*v0_.z; pv[3]  += p_*v0_.w; \
  pv[4]  += p_*v1_.x; pv[5]  += p_*v1_.y; pv[6]  += p_*v1_.z; pv[7]  += p_*v1_.w; \
  pv[8]  += p_*v2_.x; pv[9]  += p_*v2_.y; pv[10] += p_*v2_.z; pv[11] += p_*v2_.w; \
  pv[12] += p_*v3_.x; pv[13] += p_*v3_.y; pv[14] += p_*v3_.z; pv[15] += p_*v3_.w;

    int e = 0;
    for (; e + 2 <= dg; e += 2) {
      int sn0 = meta[p0 + e], sn1 = meta[p0 + e + 1];
      const float4* r0 = (const float4*)(kv + (size_t)sn0 * 256 + c * DKH);
      const float4* r1 = (const float4*)(kv + (size_t)sn1 * 256 + c * DKH);
      float4 ka0 = r0[0], kb0 = r0[1], kc0 = r0[2], kd0 = r0[3];
      float4 va0 = r0[32], vb0 = r0[33], vc0 = r0[34], vd0 = r0[35];
      float4 ka1 = r1[0], kb1 = r1[1], kc1 = r1[2], kd1 = r1[3];
      float4 va1 = r1[32], vb1 = r1[33], vc1 = r1[34], vd1 = r1[35];
      float s0 = SCORE(ka0, kb0, kc0, kd0);
      float s1 = SCORE(ka1, kb1, kc1, kd1);
      float p0e = __expf(s0 * pri);
      float p1e = __expf(s1 * pri);
      den += p0e + p1e;
      PVADD(p0e, va0, vb0, vc0, vd0);
      PVADD(p1e, va1, vb1, vc1, vd1);
    }
    if (e < dg) {
      int sn0 = meta[p0 + e];
      const float4* r0 = (const float4*)(kv + (size_t)sn0 * 256 + c * DKH);
      float4 ka0 = r0[0], kb0 = r0[1], kc0 = r0[2], kd0 = r0[3];
      float4 va0 = r0[32], vb0 = r0[33], vc0 = r0[34], vd0 = r0[35];
      float s0 = SCORE(ka0, kb0, kc0, kd0);
      float p0e = __expf(s0 * pri);
      den += p0e;
      PVADD(p0e, va0, vb0, vc0, vd0);
    }
#undef SCORE
#undef PVADD

    // tacc += (pv @ M[r,c]) / den   (global M reads, broadcast-coalesced)
    const float* Mb = rel_msg + (size_t)(r * NH + c) * 256;
    float o[16];
    #pragma unroll
    for (int j = 0; j < 16; j++) o[j] = 0.f;
    #pragma unroll
    for (int d = 0; d < 16; d++) {
      const float4* mr = (const float4*)(Mb + d * 16);
      float4 m0 = mr[0], m1 = mr[1], m2 = mr[2], m3 = mr[3];
      float p = pv[d];
      o[0]  += p*m0.x; o[1]  += p*m0.y; o[2]  += p*m0.z; o[3]  += p*m0.w;
      o[4]  += p*m1.x; o[5]  += p*m1.y; o[6]  += p*m1.z; o[7]  += p*m1.w;
      o[8]  += p*m2.x; o[9]  += p*m2.y; o[10] += p*m2.z; o[11] += p*m2.w;
      o[12] += p*m3.x; o[13] += p*m3.y; o[14] += p*m3.z; o[15] += p*m3.w;
    }
    float inv = 1.f / den;
    #pragma unroll
    for (int j = 0; j < 16; j++) tacc[j] += o[j] * inv;
  }

  float s = 1.f / fmaxf(cnt, 1.f);
  float4* tw = (float4*)(tout + (size_t)n * DIM + c * DKH);
  tw[0] = make_float4(tacc[0]*s,  tacc[1]*s,  tacc[2]*s,  tacc[3]*s);
  tw[1] = make_float4(tacc[4]*s,  tacc[5]*s,  tacc[6]*s,  tacc[7]*s);
  tw[2] = make_float4(tacc[8]*s,  tacc[9]*s,  tacc[10]*s, tacc[11]*s);
  tw[3] = make_float4(tacc[12]*s, tacc[13]*s, tacc[14]*s, tacc[15]*s);
}

// ---------------------------------------------------------------------------
// wa_gemm_ln: Wa typed projection reading tbuf, with skip-blend + per-type
// LayerNorm fused into the epilogue. Col-split conflict-free LDS as kqv_gemm.
// ---------------------------------------------------------------------------
__launch_bounds__(256)
__global__ void wa_gemm_ln(const float* __restrict__ tbuf,
                           const float* __restrict__ Wa, const float* __restrict__ ba,
                           const float* __restrict__ x, const float* __restrict__ skip,
                           const float* __restrict__ ln_g, const float* __restrict__ ln_b,
                           float* __restrict__ out,
                           const int* __restrict__ order, const int* __restrict__ bcnt) {
  int t = blockIdx.y;
  int cnt = bcnt[t];
  int base = blockIdx.x * 64;
  if (base >= cnt) return;

  __shared__ float xs[64][129];
  __shared__ __align__(16) float wsl[8 * 128];
  __shared__ int nids[64];

  int tid = threadIdx.x;
  if (tid < 64) {
    int idx = base + tid;
    nids[tid] = (idx < cnt) ? order[t * N_NODES + idx] : -1;
  }
  __syncthreads();

  #pragma unroll
  for (int i = 0; i < 8; i++) {
    int idx = tid + i * 256;
    int node = idx >> 5, c4 = idx & 31;
    int nid = nids[node];
    float4 v = make_float4(0.f, 0.f, 0.f, 0.f);
    if (nid >= 0) v = *(const float4*)(tbuf + (size_t)nid * DIM + c4 * 4);
    xs[node][c4 * 4 + 0] = v.x;
    xs[node][c4 * 4 + 1] = v.y;
    xs[node][c4 * 4 + 2] = v.z;
    xs[node][c4 * 4 + 3] = v.w;
  }

  const float* wbase = Wa + (size_t)t * DIM * DIM;
  int tx = tid & 15;
  int ty = tid >> 4;
  float4 acc[4][2];
  #pragma unroll
  for (int j = 0; j < 4; j++) {
    acc[j][0] = make_float4(0.f, 0.f, 0.f, 0.f);
    acc[j][1] = make_float4(0.f, 0.f, 0.f, 0.f);
  }

  for (int ks = 0; ks < 16; ks++) {            // 8 k-rows per stage
    __syncthreads();
    *(float4*)&wsl[tid * 4] = *(const float4*)(wbase + ks * 1024 + tid * 4);
    __syncthreads();
    #pragma unroll
    for (int kk = 0; kk < 8; kk++) {
      float4 w0 = *(const float4*)&wsl[kk * 128 + tx * 4];
      float4 w1 = *(const float4*)&wsl[kk * 128 + 64 + tx * 4];
      #pragma unroll
      for (int j = 0; j < 4; j++) {
        float xv = xs[ty * 4 + j][ks * 8 + kk];
        acc[j][0].x += xv * w0.x; acc[j][0].y += xv * w0.y;
        acc[j][0].z += xv * w0.z; acc[j][0].w += xv * w0.w;
        acc[j][1].x += xv * w1.x; acc[j][1].y += xv * w1.y;
        acc[j][1].z += xv * w1.z; acc[j][1].w += xv * w1.w;
      }
    }
  }

  // epilogue: bias + skip-blend + LayerNorm + affine, write d_out
  float alpha = 1.f / (1.f + __expf(-skip[t]));
  float beta = 1.f - alpha;
  float4 b0 = *(const float4*)(ba + t * DIM + tx * 4);
  float4 b1 = *(const float4*)(ba + t * DIM + 64 + tx * 4);
  float4 g0 = *(const float4*)(ln_g + t * DIM + tx * 4);
  float4 g1 = *(const float4*)(ln_g + t * DIM + 64 + tx * 4);
  float4 e0 = *(const float4*)(ln_b + t * DIM + tx * 4);
  float4 e1 = *(const float4*)(ln_b + t * DIM + 64 + tx * 4);

  #pragma unroll
  for (int j = 0; j < 4; j++) {
    int nid = nids[ty * 4 + j];        // uniform across the 16-lane tx group
    if (nid < 0) continue;
    float4 xa = *(const float4*)(x + (size_t)nid * DIM + tx * 4);
    float4 xb = *(const float4*)(x + (size_t)nid * DIM + 64 + tx * 4);
    float o[8];
    o[0] = (acc[j][0].x + b0.x) * alpha + xa.x * beta;
    o[1] = (acc[j][0].y + b0.y) * alpha + xa.y * beta;
    o[2] = (acc[j][0].z + b0.z) * alpha + xa.z * beta;
    o[3] = (acc[j][0].w + b0.w) * alpha + xa.w * beta;
    o[4] = (acc[j][1].x + b1.x) * alpha + xb.x * beta;
    o[5] = (acc[j][1].y + b1.y) * alpha + xb.y * beta;
    o[6] = (acc[j][1].z + b1.z) * alpha + xb.z * beta;
    o[7] = (acc[j][1].w + b1.w) * alpha + xb.w * beta;
    float s = o[0]+o[1]+o[2]+o[3]+o[4]+o[5]+o[6]+o[7];
    #pragma unroll
    for (int m = 1; m <= 8; m <<= 1) s += __shfl_xor(s, m);
    float mu = s * (1.f / 128.f);
    float sq = 0.f;
    #pragma unroll
    for (int i = 0; i < 8; i++) { o[i] -= mu; sq += o[i] * o[i]; }
    #pragma unroll
    for (int m = 1; m <= 8; m <<= 1) sq += __shfl_xor(sq, m);
    float rs = rsqrtf(sq * (1.f / 128.f) + 1e-5f);
    float* ob = out + (size_t)nid * DIM;
    *(float4*)(ob + tx * 4)      = make_float4(o[0]*rs*g0.x + e0.x, o[1]*rs*g0.y + e0.y,
                                               o[2]*rs*g0.z + e0.z, o[3]*rs*g0.w + e0.w);
    *(float4*)(ob + 64 + tx * 4) = make_float4(o[4]*rs*g1.x + e1.x, o[5]*rs*g1.y + e1.y,
                                               o[6]*rs*g1.z + e1.z, o[7]*rs*g1.w + e1.w);
  }
}

// ---------------------------------------------------------------------------
extern "C" void kernel_launch(void* const* d_in, const int* in_sizes, int n_in,
                              void* d_out, int out_size, void* d_ws, size_t ws_size,
                              hipStream_t stream) {
  const float* x       = (const float*)d_in[0];
  const int*   ntype   = (const int*)  d_in[1];
  const int*   src     = (const int*)  d_in[2];
  const int*   dst     = (const int*)  d_in[3];
  const int*   etype   = (const int*)  d_in[4];
  const float* Wk      = (const float*)d_in[5];
  const float* bk      = (const float*)d_in[6];
  const float* Wq      = (const float*)d_in[7];
  const float* bq      = (const float*)d_in[8];
  const float* Wv      = (const float*)d_in[9];
  const float* bv      = (const float*)d_in[10];
  const float* Wa      = (const float*)d_in[11];
  const float* ba      = (const float*)d_in[12];
  const float* rel_pri = (const float*)d_in[13];
  const float* rel_att = (const float*)d_in[14];
  const float* rel_msg = (const float*)d_in[15];
  const float* skip    = (const float*)d_in[16];
  const float* ln_g    = (const float*)d_in[17];
  const float* ln_b    = (const float*)d_in[18];
  float* out = (float*)d_out;

  // workspace layout (floats/ints); total ~27.5M elems ~= 110 MB
  float* ws = (float*)d_ws;
  size_t o = 0;
  float* kvbuf = ws + o; o += (size_t)N_NODES * 256;  // 12.8M (k|v interleaved)
  float* qbuf  = ws + o; o += (size_t)N_NODES * DIM;  // 6.4M
  float* tbuf  = ws + o; o += (size_t)N_NODES * DIM;  // 6.4M (fully written)
  int* order    = (int*)(ws + o); o += (size_t)N_NODES * NT;  // 0.15M
  int* meta     = (int*)(ws + o); o += (size_t)N_EDGES;       // 0.5M (fully written)
  int* segstart = (int*)(ws + o); o += (size_t)NSEG;          // 0.25M (fully written)
  // contiguous zero region: deg + cursor + cnts
  int* deg     = (int*)(ws + o); o += (size_t)NSEG;          // 0.25M
  int* cursor  = (int*)(ws + o); o += (size_t)NSEG;          // 0.25M
  int* cnts    = (int*)(ws + o); o += 8;   // [0..2]=bcnt, [4]=gcursor
  (void)ws_size; (void)in_sizes; (void)n_in; (void)out_size;

  long nzero_ints = (long)NSEG * 2 + 8;
  init_ints<<<512, 256, 0, stream>>>(deg, nzero_ints);

  bucket_nodes<<<(N_NODES + 255) / 256, 256, 0, stream>>>(ntype, order, cnts);
  hist_seg<<<(N_EDGES + 255) / 256, 256, 0, stream>>>(dst, etype, deg);
  assign_seg<<<(NSEG + 255) / 256, 256, 0, stream>>>(deg, segstart, cnts + 4);
  scatter_seg<<<(N_EDGES + 255) / 256, 256, 0, stream>>>(src, dst, etype, segstart,
                                                         cursor, meta);

  dim3 gg((N_NODES + 63) / 64, NT);
  kqv_gemm<<<gg, 256, 0, stream>>>(x, Wk, bk, Wq, bq, Wv, bv, kvbuf, qbuf, order, cnts);

  rel_gather<<<(N_NODES + 31) / 32, 256, 0, stream>>>(kvbuf, qbuf, rel_att, rel_msg,
                                                      rel_pri, segstart, deg, meta, tbuf);

  wa_gemm_ln<<<gg, 256, 0, stream>>>(tbuf, Wa, ba, x, skip, ln_g, ln_b, out,
                                     order, cnts);
}

// Round 12
// 421.899 us; speedup vs baseline: 1.8561x; 1.8561x over previous
//
#include <hip/hip_runtime.h>
#include <math.h>

#define N_NODES 50000
#define N_EDGES 500000
#define NT 3
#define NRR 5
#define NH 8
#define DKH 16
#define DIM 128
#define NSEG (N_NODES * NRR)

// ---------------------------------------------------------------------------
// init: zero deg + cursor + cnts (contiguous int region, ~2 MB)
// ---------------------------------------------------------------------------
__global__ void init_ints(int* __restrict__ base, long n_ints) {
  long i = (long)blockIdx.x * blockDim.x + threadIdx.x;
  long stride = (long)gridDim.x * blockDim.x;
  for (long j = i; j < n_ints; j += stride) base[j] = 0;
}

// ---------------------------------------------------------------------------
// bucket nodes by type, LDS-preaggregated (3 global atomics per block, G12)
// ---------------------------------------------------------------------------
__global__ void bucket_nodes(const int* __restrict__ ntype, int* __restrict__ order,
                             int* __restrict__ bcnt) {
  __shared__ int lcnt[NT];
  __shared__ int lbase[NT];
  int tid = threadIdx.x;
  if (tid < NT) lcnt[tid] = 0;
  __syncthreads();
  int i = blockIdx.x * blockDim.x + tid;
  int t = -1, lp = 0;
  if (i < N_NODES) {
    t = ntype[i];
    lp = atomicAdd(&lcnt[t], 1);
  }
  __syncthreads();
  if (tid < NT) lbase[tid] = atomicAdd(&bcnt[tid], lcnt[tid]);
  __syncthreads();
  if (i < N_NODES) order[t * N_NODES + lbase[t] + lp] = i;
}

// ---------------------------------------------------------------------------
// segment CSR build: histogram over seg=(dst*R+etype), then UNORDERED range
// assignment (wave shfl_up scan + one global atomic per block).
// ---------------------------------------------------------------------------
__global__ void hist_seg(const int* __restrict__ dst, const int* __restrict__ etype,
                         int* __restrict__ deg) {
  int i = blockIdx.x * blockDim.x + threadIdx.x;
  if (i >= N_EDGES) return;
  atomicAdd(&deg[dst[i] * NRR + etype[i]], 1);   // 250K addrs, avg contention 2
}

__global__ void assign_seg(const int* __restrict__ deg, int* __restrict__ segstart,
                           int* __restrict__ gcursor) {
  int i = blockIdx.x * 256 + threadIdx.x;
  int lane = threadIdx.x & 63, wv = threadIdx.x >> 6;
  int d = (i < NSEG) ? deg[i] : 0;
  int s = d;                                  // inclusive scan within wave
  #pragma unroll
  for (int m = 1; m < 64; m <<= 1) {
    int v = __shfl_up(s, m, 64);
    if (lane >= m) s += v;
  }
  __shared__ int wsum[4];
  __shared__ int wbase[4];
  __shared__ int blockbase;
  if (lane == 63) wsum[wv] = s;
  __syncthreads();
  if (threadIdx.x == 0) {
    int acc = 0;
    #pragma unroll
    for (int w = 0; w < 4; w++) { wbase[w] = acc; acc += wsum[w]; }
    blockbase = atomicAdd(gcursor, acc);
  }
  __syncthreads();
  if (i < NSEG) segstart[i] = blockbase + wbase[wv] + (s - d);   // exclusive
}

__global__ void scatter_seg(const int* __restrict__ src, const int* __restrict__ dst,
                            const int* __restrict__ etype,
                            const int* __restrict__ segstart, int* __restrict__ cursor,
                            int* __restrict__ meta) {
  int i = blockIdx.x * blockDim.x + threadIdx.x;
  if (i >= N_EDGES) return;
  int seg = dst[i] * NRR + etype[i];
  int pos = segstart[seg] + atomicAdd(&cursor[seg], 1);
  meta[pos] = src[i];
}

// ---------------------------------------------------------------------------
// kqv_gemm: fused K/Q/V typed projections (R10 version, conflicts fixed).
// Lane tx owns cols [tx*4,+4) and [64+tx*4,+4); W staged 8 k-rows (4KB).
// k,v written interleaved per node (kv[n][0..127]=k, [128..255]=v).
// ---------------------------------------------------------------------------
__launch_bounds__(256)
__global__ void kqv_gemm(const float* __restrict__ x,
                         const float* __restrict__ Wk, const float* __restrict__ bk,
                         const float* __restrict__ Wq, const float* __restrict__ bq,
                         const float* __restrict__ Wv, const float* __restrict__ bv,
                         float* __restrict__ kv, float* __restrict__ qb,
                         const int* __restrict__ order, const int* __restrict__ bcnt) {
  int t = blockIdx.y;
  int cnt = bcnt[t];
  int base = blockIdx.x * 64;
  if (base >= cnt) return;

  __shared__ float xs[64][129];
  __shared__ __align__(16) float wsl[8 * 128];
  __shared__ int nids[64];

  int tid = threadIdx.x;
  if (tid < 64) {
    int idx = base + tid;
    nids[tid] = (idx < cnt) ? order[t * N_NODES + idx] : -1;
  }
  __syncthreads();

  #pragma unroll
  for (int i = 0; i < 8; i++) {
    int idx = tid + i * 256;
    int node = idx >> 5, c4 = idx & 31;
    int nid = nids[node];
    float4 v = make_float4(0.f, 0.f, 0.f, 0.f);
    if (nid >= 0) v = *(const float4*)(x + (size_t)nid * DIM + c4 * 4);
    xs[node][c4 * 4 + 0] = v.x;
    xs[node][c4 * 4 + 1] = v.y;
    xs[node][c4 * 4 + 2] = v.z;
    xs[node][c4 * 4 + 3] = v.w;
  }

  int tx = tid & 15;
  int ty = tid >> 4;
  const float* Ws[3] = {Wk, Wv, Wq};
  const float* bs[3] = {bk, bv, bq};

  for (int m = 0; m < 3; m++) {
    const float* wbase = Ws[m] + (size_t)t * DIM * DIM;
    float4 acc[4][2];
    #pragma unroll
    for (int j = 0; j < 4; j++) {
      acc[j][0] = make_float4(0.f, 0.f, 0.f, 0.f);
      acc[j][1] = make_float4(0.f, 0.f, 0.f, 0.f);
    }

    for (int ks = 0; ks < 16; ks++) {          // 8 k-rows per stage
      __syncthreads();
      *(float4*)&wsl[tid * 4] = *(const float4*)(wbase + ks * 1024 + tid * 4);
      __syncthreads();
      #pragma unroll
      for (int kk = 0; kk < 8; kk++) {
        float4 w0 = *(const float4*)&wsl[kk * 128 + tx * 4];
        float4 w1 = *(const float4*)&wsl[kk * 128 + 64 + tx * 4];
        #pragma unroll
        for (int j = 0; j < 4; j++) {
          float xv = xs[ty * 4 + j][ks * 8 + kk];
          acc[j][0].x += xv * w0.x; acc[j][0].y += xv * w0.y;
          acc[j][0].z += xv * w0.z; acc[j][0].w += xv * w0.w;
          acc[j][1].x += xv * w1.x; acc[j][1].y += xv * w1.y;
          acc[j][1].z += xv * w1.z; acc[j][1].w += xv * w1.w;
        }
      }
    }

    float4 b0 = *(const float4*)(bs[m] + t * DIM + tx * 4);
    float4 b1 = *(const float4*)(bs[m] + t * DIM + 64 + tx * 4);
    #pragma unroll
    for (int j = 0; j < 4; j++) {
      int nid = nids[ty * 4 + j];
      if (nid < 0) continue;
      float* ob = (m == 2) ? (qb + (size_t)nid * DIM)
                           : (kv + (size_t)nid * 256 + (m == 1 ? 128 : 0));
      *(float4*)(ob + tx * 4)      = make_float4(acc[j][0].x + b0.x, acc[j][0].y + b0.y,
                                                 acc[j][0].z + b0.z, acc[j][0].w + b0.w);
      *(float4*)(ob + 64 + tx * 4) = make_float4(acc[j][1].x + b1.x, acc[j][1].y + b1.y,
                                                 acc[j][1].z + b1.z, acc[j][1].w + b1.w);
    }
  }
}

// ---------------------------------------------------------------------------
// rel_gather v4 (reverted from v5; v5's global A/M + serial r-loop + 128 VGPR
// was 4.6x slower): lane=head, 8-lane group=segment, wave=8 segments,
// 2-edge unroll. A[r],M[r] staged in LDS [8][260] (conflict-free) — this
// staging is load-bearing (R11 lesson). hseg pre-normalized; denom=0 = empty.
// grid = (ceil(N/32), R); block 256.
// ---------------------------------------------------------------------------
__launch_bounds__(256)
__global__ void rel_gather(const float* __restrict__ kv, const float* __restrict__ qmat,
                           const float* __restrict__ rel_att, const float* __restrict__ rel_msg,
                           const float* __restrict__ rel_pri,
                           const int* __restrict__ segstart, const int* __restrict__ deg,
                           const int* __restrict__ meta,
                           float* __restrict__ denom, float* __restrict__ hseg) {
  int r = blockIdx.y;
  int tid = threadIdx.x;

  __shared__ __align__(16) float As[8 * 260];
  __shared__ __align__(16) float Ms[8 * 260];
  {
    int idx = tid * 8;               // 2048 floats each, 8 per thread
    int hh = idx >> 8, w = idx & 255;
    const float4* ga = (const float4*)(rel_att + (size_t)r * 2048 + idx);
    *(float4*)&As[hh * 260 + w] = ga[0];
    *(float4*)&As[hh * 260 + w + 4] = ga[1];
    const float4* gm = (const float4*)(rel_msg + (size_t)r * 2048 + idx);
    *(float4*)&Ms[hh * 260 + w] = gm[0];
    *(float4*)&Ms[hh * 260 + w + 4] = gm[1];
  }
  __syncthreads();

  int g = tid >> 3;                  // group 0..31 = one segment
  int c = tid & 7;                   // head owned by this lane
  int n = blockIdx.x * 32 + g;
  if (n >= N_NODES) return;
  int seg = n * NRR + r;
  int dg = deg[seg];
  if (dg == 0) {
    denom[(size_t)seg * NH + c] = 0.f;   // each lane writes its head
    return;
  }
  int p0 = segstart[seg];
  float pri = rel_pri[r * NH + c] * 0.25f;   // fold 1/sqrt(16)

  const float4* qr = (const float4*)(qmat + (size_t)n * DIM + c * DKH);
  float4 q0 = qr[0], q1 = qr[1], q2 = qr[2], q3 = qr[3];

  // qa[d] = sum_f A[c][d][f] * q[f]   (fully in-lane, LDS float4 reads)
  float qa[16];
  #pragma unroll
  for (int d = 0; d < 16; d++) {
    const float* ar = &As[c * 260 + d * 16];
    float4 a0 = *(const float4*)(ar);
    float4 a1 = *(const float4*)(ar + 4);
    float4 a2 = *(const float4*)(ar + 8);
    float4 a3 = *(const float4*)(ar + 12);
    qa[d] = a0.x*q0.x + a0.y*q0.y + a0.z*q0.z + a0.w*q0.w
          + a1.x*q1.x + a1.y*q1.y + a1.z*q1.z + a1.w*q1.w
          + a2.x*q2.x + a2.y*q2.y + a2.z*q2.z + a2.w*q2.w
          + a3.x*q3.x + a3.y*q3.y + a3.z*q3.z + a3.w*q3.w;
  }

  float den = 0.f;
  float pv[16];
  #pragma unroll
  for (int d = 0; d < 16; d++) pv[d] = 0.f;

#define SCORE(k0_, k1_, k2_, k3_) \
  (k0_.x*qa[0]  + k0_.y*qa[1]  + k0_.z*qa[2]  + k0_.w*qa[3]  \
 + k1_.x*qa[4]  + k1_.y*qa[5]  + k1_.z*qa[6]  + k1_.w*qa[7]  \
 + k2_.x*qa[8]  + k2_.y*qa[9]  + k2_.z*qa[10] + k2_.w*qa[11] \
 + k3_.x*qa[12] + k3_.y*qa[13] + k3_.z*qa[14] + k3_.w*qa[15])

#define PVADD(p_, v0_, v1_, v2_, v3_) \
  pv[0]  += p_*v0_.x; pv[1]  += p_*v0_.y; pv[2]  += p_*v0_.z; pv[3]  += p_*v0_.w; \
  pv[4]  += p_*v1_.x; pv[5]  += p_*v1_.y; pv[6]  += p_*v1_.z; pv[7]  += p_*v1_.w; \
  pv[8]  += p_*v2_.x; pv[9]  += p_*v2_.y; pv[10] += p_*v2_.z; pv[11] += p_*v2_.w; \
  pv[12] += p_*v3_.x; pv[13] += p_*v3_.y; pv[14] += p_*v3_.z; pv[15] += p_*v3_.w;

  int e = 0;
  for (; e + 2 <= dg; e += 2) {
    int sn0 = meta[p0 + e], sn1 = meta[p0 + e + 1];
    const float4* r0 = (const float4*)(kv + (size_t)sn0 * 256 + c * DKH);
    const float4* r1 = (const float4*)(kv + (size_t)sn1 * 256 + c * DKH);
    float4 ka0 = r0[0], kb0 = r0[1], kc0 = r0[2], kd0 = r0[3];
    float4 va0 = r0[32], vb0 = r0[33], vc0 = r0[34], vd0 = r0[35];
    float4 ka1 = r1[0], kb1 = r1[1], kc1 = r1[2], kd1 = r1[3];
    float4 va1 = r1[32], vb1 = r1[33], vc1 = r1[34], vd1 = r1[35];
    float s0 = SCORE(ka0, kb0, kc0, kd0);
    float s1 = SCORE(ka1, kb1, kc1, kd1);
    float p0e = __expf(s0 * pri);
    float p1e = __expf(s1 * pri);
    den += p0e + p1e;
    PVADD(p0e, va0, vb0, vc0, vd0);
    PVADD(p1e, va1, vb1, vc1, vd1);
  }
  if (e < dg) {
    int sn0 = meta[p0 + e];
    const float4* r0 = (const float4*)(kv + (size_t)sn0 * 256 + c * DKH);
    float4 ka0 = r0[0], kb0 = r0[1], kc0 = r0[2], kd0 = r0[3];
    float4 va0 = r0[32], vb0 = r0[33], vc0 = r0[34], vd0 = r0[35];
    float s0 = SCORE(ka0, kb0, kc0, kd0);
    float p0e = __expf(s0 * pri);
    den += p0e;
    PVADD(p0e, va0, vb0, vc0, vd0);
  }
#undef SCORE
#undef PVADD

  // out[j] = (sum_d pv[d] * M[c][d][j]) / den
  float o[16];
  #pragma unroll
  for (int j = 0; j < 16; j++) o[j] = 0.f;
  #pragma unroll
  for (int d = 0; d < 16; d++) {
    const float* mr = &Ms[c * 260 + d * 16];
    float4 m0 = *(const float4*)(mr);
    float4 m1 = *(const float4*)(mr + 4);
    float4 m2 = *(const float4*)(mr + 8);
    float4 m3 = *(const float4*)(mr + 12);
    float p = pv[d];
    o[0]  += p*m0.x; o[1]  += p*m0.y; o[2]  += p*m0.z; o[3]  += p*m0.w;
    o[4]  += p*m1.x; o[5]  += p*m1.y; o[6]  += p*m1.z; o[7]  += p*m1.w;
    o[8]  += p*m2.x; o[9]  += p*m2.y; o[10] += p*m2.z; o[11] += p*m2.w;
    o[12] += p*m3.x; o[13] += p*m3.y; o[14] += p*m3.z; o[15] += p*m3.w;
  }
  float inv = 1.f / den;
  float4* hw = (float4*)(hseg + (size_t)seg * DIM + c * DKH);
  hw[0] = make_float4(o[0]*inv,  o[1]*inv,  o[2]*inv,  o[3]*inv);
  hw[1] = make_float4(o[4]*inv,  o[5]*inv,  o[6]*inv,  o[7]*inv);
  hw[2] = make_float4(o[8]*inv,  o[9]*inv,  o[10]*inv, o[11]*inv);
  hw[3] = make_float4(o[12]*inv, o[13]*inv, o[14]*inv, o[15]*inv);
  denom[(size_t)seg * NH + c] = den;
}

// ---------------------------------------------------------------------------
// wa_gemm_ln: Wa typed projection with (a) cross-relation mean fused into
// staging and (b) skip-blend + per-type LayerNorm fused into the epilogue.
// Same col-split bank-conflict fix + 4KB W stage as kqv_gemm.
// ---------------------------------------------------------------------------
__launch_bounds__(256)
__global__ void wa_gemm_ln(const float* __restrict__ hseg, const float* __restrict__ denom,
                           const float* __restrict__ Wa, const float* __restrict__ ba,
                           const float* __restrict__ x, const float* __restrict__ skip,
                           const float* __restrict__ ln_g, const float* __restrict__ ln_b,
                           float* __restrict__ out,
                           const int* __restrict__ order, const int* __restrict__ bcnt) {
  int t = blockIdx.y;
  int cnt = bcnt[t];
  int base = blockIdx.x * 64;
  if (base >= cnt) return;

  __shared__ float xs[64][129];
  __shared__ __align__(16) float wsl[8 * 128];
  __shared__ int nids[64];

  int tid = threadIdx.x;
  if (tid < 64) {
    int idx = base + tid;
    nids[tid] = (idx < cnt) ? order[t * N_NODES + idx] : -1;
  }
  __syncthreads();

  // stage t[n,:] = mean over nonempty r of hseg (pre-normalized)
  #pragma unroll
  for (int i = 0; i < 8; i++) {
    int idx = tid + i * 256;
    int node = idx >> 5, c4 = idx & 31;
    int nid = nids[node];
    float4 v = make_float4(0.f, 0.f, 0.f, 0.f);
    if (nid >= 0) {
      int h = c4 >> 2;
      float cn = 0.f;
      float4 a = make_float4(0.f, 0.f, 0.f, 0.f);
      #pragma unroll
      for (int rr = 0; rr < NRR; rr++) {
        float den = denom[((size_t)nid * NRR + rr) * NH + h];
        if (den > 0.f) {
          float4 hv = *(const float4*)(hseg + ((size_t)nid * NRR + rr) * DIM + c4 * 4);
          a.x += hv.x; a.y += hv.y; a.z += hv.z; a.w += hv.w;
          cn += 1.f;
        }
      }
      float s = 1.f / fmaxf(cn, 1.f);
      v = make_float4(a.x * s, a.y * s, a.z * s, a.w * s);
    }
    xs[node][c4 * 4 + 0] = v.x;
    xs[node][c4 * 4 + 1] = v.y;
    xs[node][c4 * 4 + 2] = v.z;
    xs[node][c4 * 4 + 3] = v.w;
  }

  const float* wbase = Wa + (size_t)t * DIM * DIM;
  int tx = tid & 15;
  int ty = tid >> 4;
  float4 acc[4][2];
  #pragma unroll
  for (int j = 0; j < 4; j++) {
    acc[j][0] = make_float4(0.f, 0.f, 0.f, 0.f);
    acc[j][1] = make_float4(0.f, 0.f, 0.f, 0.f);
  }

  for (int ks = 0; ks < 16; ks++) {            // 8 k-rows per stage
    __syncthreads();
    *(float4*)&wsl[tid * 4] = *(const float4*)(wbase + ks * 1024 + tid * 4);
    __syncthreads();
    #pragma unroll
    for (int kk = 0; kk < 8; kk++) {
      float4 w0 = *(const float4*)&wsl[kk * 128 + tx * 4];
      float4 w1 = *(const float4*)&wsl[kk * 128 + 64 + tx * 4];
      #pragma unroll
      for (int j = 0; j < 4; j++) {
        float xv = xs[ty * 4 + j][ks * 8 + kk];
        acc[j][0].x += xv * w0.x; acc[j][0].y += xv * w0.y;
        acc[j][0].z += xv * w0.z; acc[j][0].w += xv * w0.w;
        acc[j][1].x += xv * w1.x; acc[j][1].y += xv * w1.y;
        acc[j][1].z += xv * w1.z; acc[j][1].w += xv * w1.w;
      }
    }
  }

  // epilogue: bias + skip-blend + LayerNorm + affine, write d_out
  float alpha = 1.f / (1.f + __expf(-skip[t]));
  float beta = 1.f - alpha;
  float4 b0 = *(const float4*)(ba + t * DIM + tx * 4);
  float4 b1 = *(const float4*)(ba + t * DIM + 64 + tx * 4);
  float4 g0 = *(const float4*)(ln_g + t * DIM + tx * 4);
  float4 g1 = *(const float4*)(ln_g + t * DIM + 64 + tx * 4);
  float4 e0 = *(const float4*)(ln_b + t * DIM + tx * 4);
  float4 e1 = *(const float4*)(ln_b + t * DIM + 64 + tx * 4);

  #pragma unroll
  for (int j = 0; j < 4; j++) {
    int nid = nids[ty * 4 + j];        // uniform across the 16-lane tx group
    if (nid < 0) continue;
    float4 xa = *(const float4*)(x + (size_t)nid * DIM + tx * 4);
    float4 xb = *(const float4*)(x + (size_t)nid * DIM + 64 + tx * 4);
    float o[8];
    o[0] = (acc[j][0].x + b0.x) * alpha + xa.x * beta;
    o[1] = (acc[j][0].y + b0.y) * alpha + xa.y * beta;
    o[2] = (acc[j][0].z + b0.z) * alpha + xa.z * beta;
    o[3] = (acc[j][0].w + b0.w) * alpha + xa.w * beta;
    o[4] = (acc[j][1].x + b1.x) * alpha + xb.x * beta;
    o[5] = (acc[j][1].y + b1.y) * alpha + xb.y * beta;
    o[6] = (acc[j][1].z + b1.z) * alpha + xb.z * beta;
    o[7] = (acc[j][1].w + b1.w) * alpha + xb.w * beta;
    float s = o[0]+o[1]+o[2]+o[3]+o[4]+o[5]+o[6]+o[7];
    #pragma unroll
    for (int m = 1; m <= 8; m <<= 1) s += __shfl_xor(s, m);
    float mu = s * (1.f / 128.f);
    float sq = 0.f;
    #pragma unroll
    for (int i = 0; i < 8; i++) { o[i] -= mu; sq += o[i] * o[i]; }
    #pragma unroll
    for (int m = 1; m <= 8; m <<= 1) sq += __shfl_xor(sq, m);
    float rs = rsqrtf(sq * (1.f / 128.f) + 1e-5f);
    float* ob = out + (size_t)nid * DIM;
    *(float4*)(ob + tx * 4)      = make_float4(o[0]*rs*g0.x + e0.x, o[1]*rs*g0.y + e0.y,
                                               o[2]*rs*g0.z + e0.z, o[3]*rs*g0.w + e0.w);
    *(float4*)(ob + 64 + tx * 4) = make_float4(o[4]*rs*g1.x + e1.x, o[5]*rs*g1.y + e1.y,
                                               o[6]*rs*g1.z + e1.z, o[7]*rs*g1.w + e1.w);
  }
}

// ---------------------------------------------------------------------------
extern "C" void kernel_launch(void* const* d_in, const int* in_sizes, int n_in,
                              void* d_out, int out_size, void* d_ws, size_t ws_size,
                              hipStream_t stream) {
  const float* x       = (const float*)d_in[0];
  const int*   ntype   = (const int*)  d_in[1];
  const int*   src     = (const int*)  d_in[2];
  const int*   dst     = (const int*)  d_in[3];
  const int*   etype   = (const int*)  d_in[4];
  const float* Wk      = (const float*)d_in[5];
  const float* bk      = (const float*)d_in[6];
  const float* Wq      = (const float*)d_in[7];
  const float* bq      = (const float*)d_in[8];
  const float* Wv      = (const float*)d_in[9];
  const float* bv      = (const float*)d_in[10];
  const float* Wa      = (const float*)d_in[11];
  const float* ba      = (const float*)d_in[12];
  const float* rel_pri = (const float*)d_in[13];
  const float* rel_att = (const float*)d_in[14];
  const float* rel_msg = (const float*)d_in[15];
  const float* skip    = (const float*)d_in[16];
  const float* ln_g    = (const float*)d_in[17];
  const float* ln_b    = (const float*)d_in[18];
  float* out = (float*)d_out;

  // workspace layout (floats/ints); total ~54.9M elems ~= 220 MB
  float* ws = (float*)d_ws;
  size_t o = 0;
  float* kvbuf = ws + o; o += (size_t)N_NODES * 256;  // 12.8M (k|v interleaved)
  float* qbuf  = ws + o; o += (size_t)N_NODES * DIM;  // 6.4M
  float* hseg  = ws + o; o += (size_t)NSEG * DIM;     // 32.0M (read only where denom>0)
  float* denom = ws + o; o += (size_t)NSEG * NH;      // 2.0M  (fully written)
  int* order    = (int*)(ws + o); o += (size_t)N_NODES * NT;  // 0.15M
  int* meta     = (int*)(ws + o); o += (size_t)N_EDGES;       // 0.5M (fully written)
  int* segstart = (int*)(ws + o); o += (size_t)NSEG;          // 0.25M (fully written)
  // contiguous zero region: deg + cursor + cnts
  int* deg     = (int*)(ws + o); o += (size_t)NSEG;          // 0.25M
  int* cursor  = (int*)(ws + o); o += (size_t)NSEG;          // 0.25M
  int* cnts    = (int*)(ws + o); o += 8;   // [0..2]=bcnt, [4]=gcursor
  (void)ws_size; (void)in_sizes; (void)n_in; (void)out_size;

  long nzero_ints = (long)NSEG * 2 + 8;
  init_ints<<<512, 256, 0, stream>>>(deg, nzero_ints);

  bucket_nodes<<<(N_NODES + 255) / 256, 256, 0, stream>>>(ntype, order, cnts);
  hist_seg<<<(N_EDGES + 255) / 256, 256, 0, stream>>>(dst, etype, deg);
  assign_seg<<<(NSEG + 255) / 256, 256, 0, stream>>>(deg, segstart, cnts + 4);
  scatter_seg<<<(N_EDGES + 255) / 256, 256, 0, stream>>>(src, dst, etype, segstart,
                                                         cursor, meta);

  dim3 gg((N_NODES + 63) / 64, NT);
  kqv_gemm<<<gg, 256, 0, stream>>>(x, Wk, bk, Wq, bq, Wv, bv, kvbuf, qbuf, order, cnts);

  dim3 gr((N_NODES + 31) / 32, NRR);
  rel_gather<<<gr, 256, 0, stream>>>(kvbuf, qbuf, rel_att, rel_msg, rel_pri,
                                     segstart, deg, meta, denom, hseg);

  wa_gemm_ln<<<gg, 256, 0, stream>>>(hseg, denom, Wa, ba, x, skip, ln_g, ln_b, out,
                                     order, cnts);
}